// Round 1
// baseline (351.870 us; speedup 1.0000x reference)
//
#include <hip/hip_runtime.h>

typedef __bf16 bf16_t;
typedef __bf16 bf16x8 __attribute__((ext_vector_type(8)));
typedef float f32x4 __attribute__((ext_vector_type(4)));
typedef unsigned short u16x8 __attribute__((ext_vector_type(8)));

#define AS1C(p) ((const __attribute__((address_space(1))) void*)(p))
#define AS3(p) ((__attribute__((address_space(3))) void*)(p))

__device__ __forceinline__ unsigned short f2b_rne(float f) {
  union { float f; unsigned u; } x; x.f = f;
  unsigned u = x.u;
  u += 0x7fffu + ((u >> 16) & 1u);
  return (unsigned short)(u >> 16);
}

// ---------------- cast f32 -> bf16 (vectorized, 8 elts/thread) ----------------
__global__ __launch_bounds__(256) void cast_f32_bf16(const float* __restrict__ in,
                                                     unsigned short* __restrict__ out,
                                                     int n) {
  int i = (blockIdx.x * 256 + threadIdx.x) * 8;
  if (i >= n) return;
  const float4* p = reinterpret_cast<const float4*>(in + i);
  float4 a = p[0], b = p[1];
  u16x8 o;
  o[0] = f2b_rne(a.x); o[1] = f2b_rne(a.y); o[2] = f2b_rne(a.z); o[3] = f2b_rne(a.w);
  o[4] = f2b_rne(b.x); o[5] = f2b_rne(b.y); o[6] = f2b_rne(b.z); o[7] = f2b_rne(b.w);
  *reinterpret_cast<u16x8*>(out + i) = o;
}

// ---------------- GEMM: C[M,N] = A[M,K] * B[N,K]^T  (m97-style 128x128 tile) ----------------
template <int OUT_F32>
__global__ __launch_bounds__(256) void gemm_bt(const bf16_t* __restrict__ A,
                                               const bf16_t* __restrict__ Bm,
                                               void* __restrict__ C,
                                               int M, int N, int K, float scale) {
  __shared__ bf16_t As[128 * 32];
  __shared__ bf16_t Bs[128 * 32];
  const int tid = threadIdx.x;
  const int lane = tid & 63, wave = tid >> 6;
  const int wm = wave >> 1, wn = wave & 1;
  const int r = lane & 15, kg = lane >> 4;
  const int m0 = blockIdx.y * 128, n0 = blockIdx.x * 128;
  f32x4 acc[4][4] = {};
  const size_t abase = (size_t)m0 * K;
  const size_t bbase = (size_t)n0 * K;
  for (int k0 = 0; k0 < K; k0 += 32) {
#pragma unroll
    for (int c = 0; c < 2; ++c) {
      int e = (c * 256 + tid) * 8;
      int rr = e >> 5, cc = e & 31;
      __builtin_amdgcn_global_load_lds(AS1C(A + abase + (size_t)rr * K + k0 + cc),
                                       AS3(As + (c * 256 + wave * 64) * 8), 16, 0, 0);
      __builtin_amdgcn_global_load_lds(AS1C(Bm + bbase + (size_t)rr * K + k0 + cc),
                                       AS3(Bs + (c * 256 + wave * 64) * 8), 16, 0, 0);
    }
    __syncthreads();
    bf16x8 af[4], bfr[4];
#pragma unroll
    for (int t = 0; t < 4; ++t) {
      af[t]  = *reinterpret_cast<const bf16x8*>(As + (wm * 64 + t * 16 + r) * 32 + kg * 8);
      bfr[t] = *reinterpret_cast<const bf16x8*>(Bs + (wn * 64 + t * 16 + r) * 32 + kg * 8);
    }
#pragma unroll
    for (int i = 0; i < 4; ++i)
#pragma unroll
      for (int j = 0; j < 4; ++j)
        acc[i][j] = __builtin_amdgcn_mfma_f32_16x16x32_bf16(af[i], bfr[j], acc[i][j], 0, 0, 0);
    __syncthreads();
  }
#pragma unroll
  for (int i = 0; i < 4; ++i) {
#pragma unroll
    for (int j = 0; j < 4; ++j) {
      const int mb = m0 + wm * 64 + i * 16 + kg * 4;
      const int nc = n0 + wn * 64 + j * 16 + r;
#pragma unroll
      for (int v = 0; v < 4; ++v) {
        float val = acc[i][j][v] * scale;
        size_t idx = (size_t)(mb + v) * N + nc;
        if (OUT_F32) reinterpret_cast<float*>(C)[idx] = val;
        else reinterpret_cast<unsigned short*>(C)[idx] = f2b_rne(val);
      }
    }
  }
}

// ---------------- causal flash attention ----------------
// layouts: Q/K/V/O all [B, S, H, dk] (= GEMM output [B*S, D]), dk=64, H=16
// grid: x = q-tile (S/64), y = b*H + h.  Block 256 = 4 waves, 16 q-rows/wave.
#define S_LEN 2048
#define NH 16

__global__ __launch_bounds__(256) void flash_attn(const bf16_t* __restrict__ Q,
                                                  const bf16_t* __restrict__ K,
                                                  const bf16_t* __restrict__ V,
                                                  unsigned short* __restrict__ O) {
  __shared__ bf16_t Ks[64 * 72];   // [n][dk], +8 pad
  __shared__ bf16_t Vt[64 * 72];   // [d][n], +8 pad, chunk-XOR swizzled
  __shared__ float Sl[4][16 * 68]; // per-wave S/P tile [16][64+4]
  __shared__ float rowscale[4][16];
  __shared__ float rowsum[4][16];
  const int tid = threadIdx.x;
  const int lane = tid & 63, wave = tid >> 6;
  const int r = lane & 15, kg = lane >> 4;
  const int bh = blockIdx.y;
  const size_t head_off = (size_t)(bh / NH) * S_LEN * 1024 + (size_t)(bh % NH) * 64;
  const int q0 = blockIdx.x * 64;
  const int qrow_g = q0 + wave * 16 + r;

  // Q fragments in registers (scale 1/sqrt(dk) was folded into the Q GEMM)
  bf16x8 qf0 = *reinterpret_cast<const bf16x8*>(Q + head_off + (size_t)qrow_g * 1024 + kg * 8);
  bf16x8 qf1 = *reinterpret_cast<const bf16x8*>(Q + head_off + (size_t)qrow_g * 1024 + 32 + kg * 8);

  f32x4 oacc[4] = {};
  float m_run = -1e30f, l_run = 0.f;
  const int ntiles = blockIdx.x + 1;

  for (int t = 0; t < ntiles; ++t) {
    const int kv0 = t * 64;
    __syncthreads();  // protect K/V LDS from previous iteration's readers
#pragma unroll
    for (int c = 0; c < 2; ++c) {
      int chunk = c * 256 + tid;
      int rr = chunk >> 3, cc = (chunk & 7) * 8;
      const size_t grow = head_off + (size_t)(kv0 + rr) * 1024 + cc;
      bf16x8 k8 = *reinterpret_cast<const bf16x8*>(K + grow);
      *reinterpret_cast<bf16x8*>(Ks + rr * 72 + cc) = k8;
      bf16x8 v8 = *reinterpret_cast<const bf16x8*>(V + grow);
#pragma unroll
      for (int j = 0; j < 8; ++j) {
        int d = cc + j;
        Vt[d * 72 + (rr ^ (((d >> 3) & 3) << 3))] = v8[j];
      }
    }
    __syncthreads();

    // S = Q K^T : wave computes 16x64 scores
#pragma unroll
    for (int nt = 0; nt < 4; ++nt) {
      bf16x8 kf0 = *reinterpret_cast<const bf16x8*>(Ks + (nt * 16 + r) * 72 + kg * 8);
      bf16x8 kf1 = *reinterpret_cast<const bf16x8*>(Ks + (nt * 16 + r) * 72 + 32 + kg * 8);
      f32x4 s = {};
      s = __builtin_amdgcn_mfma_f32_16x16x32_bf16(qf0, kf0, s, 0, 0, 0);
      s = __builtin_amdgcn_mfma_f32_16x16x32_bf16(qf1, kf1, s, 0, 0, 0);
#pragma unroll
      for (int v = 0; v < 4; ++v)
        Sl[wave][(kg * 4 + v) * 68 + nt * 16 + r] = s[v];  // C layout: row=(kg*4+v), col=nt*16+r
    }

    // wave-parallel online softmax: lane handles row r, cols kg*16..kg*16+15
    float vals[16];
    float pmax = -1e30f;
#pragma unroll
    for (int cg = 0; cg < 4; ++cg) {
      f32x4 sv = *reinterpret_cast<const f32x4*>(&Sl[wave][r * 68 + kg * 16 + cg * 4]);
#pragma unroll
      for (int j = 0; j < 4; ++j) vals[cg * 4 + j] = sv[j];
    }
    if (t == ntiles - 1) {  // only the diagonal tile needs masking
#pragma unroll
      for (int ii = 0; ii < 16; ++ii) {
        int col = kv0 + kg * 16 + ii;
        if (col > qrow_g) vals[ii] = -1e30f;
      }
    }
#pragma unroll
    for (int ii = 0; ii < 16; ++ii) pmax = fmaxf(pmax, vals[ii]);
    pmax = fmaxf(pmax, __shfl_xor(pmax, 16));
    pmax = fmaxf(pmax, __shfl_xor(pmax, 32));
    const float m_new = fmaxf(m_run, pmax);
    const float alpha = __expf(m_run - m_new);
    float psum = 0.f;
#pragma unroll
    for (int ii = 0; ii < 16; ++ii) {
      float p = __expf(vals[ii] - m_new);
      vals[ii] = p;
      psum += p;
    }
    psum += __shfl_xor(psum, 16);
    psum += __shfl_xor(psum, 32);
    l_run = l_run * alpha + psum;
    m_run = m_new;
#pragma unroll
    for (int cg = 0; cg < 4; ++cg) {
      f32x4 pv;
#pragma unroll
      for (int j = 0; j < 4; ++j) pv[j] = vals[cg * 4 + j];
      *reinterpret_cast<f32x4*>(&Sl[wave][r * 68 + kg * 16 + cg * 4]) = pv;
    }
    if (lane < 16) rowscale[wave][lane] = alpha;
    float al[4];
#pragma unroll
    for (int v = 0; v < 4; ++v) al[v] = rowscale[wave][kg * 4 + v];
#pragma unroll
    for (int dt = 0; dt < 4; ++dt)
#pragma unroll
      for (int v = 0; v < 4; ++v) oacc[dt][v] *= al[v];

    // P fragments (A operand): row=r, k-chunks contiguous in Sl
    bf16x8 pa[2];
#pragma unroll
    for (int kc = 0; kc < 2; ++kc) {
      f32x4 p0 = *reinterpret_cast<const f32x4*>(&Sl[wave][r * 68 + kc * 32 + kg * 8]);
      f32x4 p1 = *reinterpret_cast<const f32x4*>(&Sl[wave][r * 68 + kc * 32 + kg * 8 + 4]);
      bf16x8 tb;
#pragma unroll
      for (int j = 0; j < 4; ++j) { tb[j] = (bf16_t)p0[j]; tb[j + 4] = (bf16_t)p1[j]; }
      pa[kc] = tb;
    }
    // O += P * V   (B operand from transposed, swizzled Vt)
#pragma unroll
    for (int dt = 0; dt < 4; ++dt) {
      const int d = dt * 16 + r;
#pragma unroll
      for (int kc = 0; kc < 2; ++kc) {
        const int nc8 = kc * 4 + kg;
        bf16x8 vb = *reinterpret_cast<const bf16x8*>(
            Vt + d * 72 + ((nc8 ^ ((d >> 3) & 3)) << 3));
        oacc[dt] = __builtin_amdgcn_mfma_f32_16x16x32_bf16(pa[kc], vb, oacc[dt], 0, 0, 0);
      }
    }
  }

  if (lane < 16) rowsum[wave][lane] = l_run;
  float inv[4];
#pragma unroll
  for (int v = 0; v < 4; ++v) inv[v] = 1.f / rowsum[wave][kg * 4 + v];
#pragma unroll
  for (int dt = 0; dt < 4; ++dt) {
    const int d = dt * 16 + r;
#pragma unroll
    for (int v = 0; v < 4; ++v) {
      const size_t srow = (size_t)(q0 + wave * 16 + kg * 4 + v);
      O[head_off + srow * 1024 + d] = f2b_rne(oacc[dt][v] * inv[v]);
    }
  }
}

// ---------------- launcher ----------------
extern "C" void kernel_launch(void* const* d_in, const int* in_sizes, int n_in,
                              void* d_out, int out_size, void* d_ws, size_t ws_size,
                              hipStream_t stream) {
  const float* x  = (const float*)d_in[0];
  const float* Wq = (const float*)d_in[1];
  const float* Wk = (const float*)d_in[2];
  const float* Wv = (const float*)d_in[3];
  const float* Wo = (const float*)d_in[4];

  char* ws = (char*)d_ws;
  bf16_t* xb  = (bf16_t*)(ws);                       // 16 MB  [8192,1024]
  bf16_t* wqb = (bf16_t*)(ws + (16u << 20));         // 2 MB
  bf16_t* wkb = (bf16_t*)(ws + (18u << 20));
  bf16_t* wvb = (bf16_t*)(ws + (20u << 20));
  bf16_t* wob = (bf16_t*)(ws + (22u << 20));
  bf16_t* qb  = (bf16_t*)(ws + (24u << 20));         // 16 MB each
  bf16_t* kb  = (bf16_t*)(ws + (40u << 20));
  bf16_t* vb  = (bf16_t*)(ws + (56u << 20));
  bf16_t* ob  = xb;  // x is dead after the V GEMM; reuse its slot for attn output

  const int NX = 4 * 2048 * 1024;  // 8,388,608
  const int NW = 1024 * 1024;      // 1,048,576
  cast_f32_bf16<<<NX / 2048, 256, 0, stream>>>(x,  (unsigned short*)xb,  NX);
  cast_f32_bf16<<<NW / 2048, 256, 0, stream>>>(Wq, (unsigned short*)wqb, NW);
  cast_f32_bf16<<<NW / 2048, 256, 0, stream>>>(Wk, (unsigned short*)wkb, NW);
  cast_f32_bf16<<<NW / 2048, 256, 0, stream>>>(Wv, (unsigned short*)wvb, NW);
  cast_f32_bf16<<<NW / 2048, 256, 0, stream>>>(Wo, (unsigned short*)wob, NW);

  dim3 gg(1024 / 128, 8192 / 128);  // (N tiles, M tiles)
  gemm_bt<0><<<gg, 256, 0, stream>>>(xb, wqb, qb, 8192, 1024, 1024, 0.125f);  // 1/sqrt(64) folded
  gemm_bt<0><<<gg, 256, 0, stream>>>(xb, wkb, kb, 8192, 1024, 1024, 1.0f);
  gemm_bt<0><<<gg, 256, 0, stream>>>(xb, wvb, vb, 8192, 1024, 1024, 1.0f);

  flash_attn<<<dim3(2048 / 64, 4 * 16), 256, 0, stream>>>(qb, kb, vb, (unsigned short*)ob);

  gemm_bt<1><<<gg, 256, 0, stream>>>(ob, wob, d_out, 8192, 1024, 1024, 1.0f);
}

// Round 3
// 211.992 us; speedup vs baseline: 1.6598x; 1.6598x over previous
//
#include <hip/hip_runtime.h>

typedef __bf16 bf16_t;
typedef __bf16 bf16x8 __attribute__((ext_vector_type(8)));
typedef __bf16 bf16x4 __attribute__((ext_vector_type(4)));
typedef float f32x4 __attribute__((ext_vector_type(4)));
typedef unsigned short u16x8 __attribute__((ext_vector_type(8)));

#define AS1C(p) ((const __attribute__((address_space(1))) void*)(p))
#define AS3(p) ((__attribute__((address_space(3))) void*)(p))

__device__ __forceinline__ unsigned short f2b_rne(float f) {
  union { float f; unsigned u; } x; x.f = f;
  unsigned u = x.u;
  u += 0x7fffu + ((u >> 16) & 1u);
  return (unsigned short)(u >> 16);
}

// ---------------- cast f32 -> bf16 (vectorized, 8 elts/thread) ----------------
__global__ __launch_bounds__(256) void cast_f32_bf16(const float* __restrict__ in,
                                                     unsigned short* __restrict__ out,
                                                     int n) {
  int i = (blockIdx.x * 256 + threadIdx.x) * 8;
  if (i >= n) return;
  const float4* p = reinterpret_cast<const float4*>(in + i);
  float4 a = p[0], b = p[1];
  u16x8 o;
  o[0] = f2b_rne(a.x); o[1] = f2b_rne(a.y); o[2] = f2b_rne(a.z); o[3] = f2b_rne(a.w);
  o[4] = f2b_rne(b.x); o[5] = f2b_rne(b.y); o[6] = f2b_rne(b.z); o[7] = f2b_rne(b.w);
  *reinterpret_cast<u16x8*>(out + i) = o;
}

// ---------------- GEMM: C[M,N] = A[M,K] * B[N,K]^T  (m97-style 128x128 tile) ----------------
// A row stride = lda (elements); scale applied to columns n0 < qlim
template <int OUT_F32>
__global__ __launch_bounds__(256) void gemm_bt(const bf16_t* __restrict__ A,
                                               const bf16_t* __restrict__ Bm,
                                               void* __restrict__ C,
                                               int M, int N, int K, int lda,
                                               float scale, int qlim) {
  __shared__ bf16_t As[128 * 32];
  __shared__ bf16_t Bs[128 * 32];
  const int tid = threadIdx.x;
  const int lane = tid & 63, wave = tid >> 6;
  const int wm = wave >> 1, wn = wave & 1;
  const int r = lane & 15, kg = lane >> 4;
  const int m0 = blockIdx.y * 128, n0 = blockIdx.x * 128;
  const float sc = (n0 < qlim) ? scale : 1.0f;
  f32x4 acc[4][4] = {};
  const size_t abase = (size_t)m0 * lda;
  const size_t bbase = (size_t)n0 * K;
  for (int k0 = 0; k0 < K; k0 += 32) {
#pragma unroll
    for (int c = 0; c < 2; ++c) {
      int e = (c * 256 + tid) * 8;
      int rr = e >> 5, cc = e & 31;
      __builtin_amdgcn_global_load_lds(AS1C(A + abase + (size_t)rr * lda + k0 + cc),
                                       AS3(As + (c * 256 + wave * 64) * 8), 16, 0, 0);
      __builtin_amdgcn_global_load_lds(AS1C(Bm + bbase + (size_t)rr * K + k0 + cc),
                                       AS3(Bs + (c * 256 + wave * 64) * 8), 16, 0, 0);
    }
    __syncthreads();
    bf16x8 af[4], bfr[4];
#pragma unroll
    for (int t = 0; t < 4; ++t) {
      af[t]  = *reinterpret_cast<const bf16x8*>(As + (wm * 64 + t * 16 + r) * 32 + kg * 8);
      bfr[t] = *reinterpret_cast<const bf16x8*>(Bs + (wn * 64 + t * 16 + r) * 32 + kg * 8);
    }
#pragma unroll
    for (int i = 0; i < 4; ++i)
#pragma unroll
      for (int j = 0; j < 4; ++j)
        acc[i][j] = __builtin_amdgcn_mfma_f32_16x16x32_bf16(af[i], bfr[j], acc[i][j], 0, 0, 0);
    __syncthreads();
  }
#pragma unroll
  for (int i = 0; i < 4; ++i) {
#pragma unroll
    for (int j = 0; j < 4; ++j) {
      const int mb = m0 + wm * 64 + i * 16 + kg * 4;
      const int nc = n0 + wn * 64 + j * 16 + r;
#pragma unroll
      for (int v = 0; v < 4; ++v) {
        float val = acc[i][j][v] * sc;
        size_t idx = (size_t)(mb + v) * N + nc;
        if (OUT_F32) reinterpret_cast<float*>(C)[idx] = val;
        else reinterpret_cast<unsigned short*>(C)[idx] = f2b_rne(val);
      }
    }
  }
}

// ---------------- V transpose: qkv V-columns [B*S][3072](+2048) -> VT [B*H][64][2048] ----------------
__global__ __launch_bounds__(256) void transpose_v(const bf16_t* __restrict__ qkv,
                                                   bf16_t* __restrict__ vt) {
  __shared__ bf16_t Vs[64 * 72];
  const int t = threadIdx.x;
  const int s0 = blockIdx.x * 64;
  const int bh = blockIdx.y;
  const int b = bh >> 4, h = bh & 15;
  const size_t in_base = ((size_t)b * 2048 + s0) * 3072 + 2048 + h * 64;
#pragma unroll
  for (int c = 0; c < 2; ++c) {
    int chunk = c * 256 + t;
    int ss = chunk >> 3, dd = (chunk & 7) * 8;
    bf16x8 v = *reinterpret_cast<const bf16x8*>(qkv + in_base + (size_t)ss * 3072 + dd);
    *reinterpret_cast<bf16x8*>(Vs + ss * 72 + dd) = v;
  }
  __syncthreads();
  const size_t out_base = (size_t)bh * 64 * 2048 + s0;
#pragma unroll
  for (int c = 0; c < 2; ++c) {
    int chunk = c * 256 + t;
    int dd = chunk >> 3, ss = (chunk & 7) * 8;
    bf16x8 o;
#pragma unroll
    for (int j = 0; j < 8; ++j) o[j] = Vs[(ss + j) * 72 + dd];
    *reinterpret_cast<bf16x8*>(vt + out_base + (size_t)dd * 2048 + ss) = o;
  }
}

// ---------------- causal flash attention ----------------
// Q,K from fused qkv [B*S][3072] (Q cols 0..1023, K cols 1024..2047), V^T from VT [B*H][64][2048]
// O is written IN-PLACE into the Q columns of qkv (ostride=3072).  Race-free: for head h,
// Q rows of tile z are read (to regs, at pass start) only by the block owning tile z, which is
// the only writer of those rows; other blocks touch other rows/columns.
// Block: 512 threads = 8 waves, 128 q-rows; grid (8, B*H); block z handles q-tiles z and 15-z.
__global__ __launch_bounds__(512) void flash_attn(const bf16_t* __restrict__ QKV,
                                                  const bf16_t* __restrict__ VT,
                                                  unsigned short* __restrict__ O,
                                                  int ostride) {
  __shared__ bf16_t Ks[64 * 72];       // K tile [n][dk], pad->2-way max
  __shared__ bf16_t Vts[64 * 72];      // V^T tile [d][n]
  __shared__ bf16_t Pl[8][16 * 72];    // per-wave P in A-frag layout [q][n]
  const int tid = threadIdx.x;
  const int lane = tid & 63, wave = tid >> 6;
  const int r = lane & 15, kg = lane >> 4;
  const int bh = blockIdx.y;
  const int b = bh >> 4, h = bh & 15;
  const size_t qkv_row0 = (size_t)b * 2048 * 3072;
  const int qcol = h * 64, kcol = 1024 + h * 64;
  const size_t vt_base = (size_t)bh * 64 * 2048;
  const size_t o_row0 = (size_t)b * 2048 * ostride;
  const int ocol = h * 64;
  const int srr = tid >> 3, scc = (tid & 7) * 8;  // staging: 512 thr x 16B = one 64x64 bf16 tile

  for (int pass = 0; pass < 2; ++pass) {
    const int qt = pass ? (15 - (int)blockIdx.x) : (int)blockIdx.x;
    const int q0 = qt * 128;
    const int qrow = q0 + wave * 16 + r;           // this lane's softmax row
    const int tmax_w = (q0 + wave * 16 + 15) >> 6; // wave's last (diagonal) tile
    const int ntiles = qt * 2 + 2;

    const size_t qoff = qkv_row0 + (size_t)qrow * 3072 + qcol;
    bf16x8 qf0 = *reinterpret_cast<const bf16x8*>(QKV + qoff + kg * 8);
    bf16x8 qf1 = *reinterpret_cast<const bf16x8*>(QKV + qoff + 32 + kg * 8);

    f32x4 oacc[4] = {};
    float m_run = -3e30f, l_run = 0.f;

    // prologue: tile 0 into regs (async-STAGE: loads always issued ahead of compute)
    bf16x8 gk = *reinterpret_cast<const bf16x8*>(QKV + qkv_row0 + (size_t)srr * 3072 + kcol + scc);
    bf16x8 gv = *reinterpret_cast<const bf16x8*>(VT + vt_base + (size_t)srr * 2048 + scc);

    for (int t = 0; t < ntiles; ++t) {
      __syncthreads();  // previous tile's LDS readers done
      *reinterpret_cast<bf16x8*>(Ks + srr * 72 + scc) = gk;
      *reinterpret_cast<bf16x8*>(Vts + srr * 72 + scc) = gv;
      __syncthreads();
      if (t + 1 < ntiles) {  // prefetch next tile; HBM latency hides under compute below
        const int kv1 = (t + 1) * 64;
        gk = *reinterpret_cast<const bf16x8*>(QKV + qkv_row0 + (size_t)(kv1 + srr) * 3072 + kcol + scc);
        gv = *reinterpret_cast<const bf16x8*>(VT + vt_base + (size_t)srr * 2048 + kv1 + scc);
      }
      if (t > tmax_w) continue;  // fully masked for this wave (barriers already passed)

      const int kv0 = t * 64;
      // S^T = mfma(K, Q): out col = q (=r), row = k-local (kg*4+v) -> row-softmax is lane-local
      float vals[16];
#pragma unroll
      for (int nt = 0; nt < 4; ++nt) {
        bf16x8 kf0 = *reinterpret_cast<const bf16x8*>(Ks + (nt * 16 + r) * 72 + kg * 8);
        bf16x8 kf1 = *reinterpret_cast<const bf16x8*>(Ks + (nt * 16 + r) * 72 + 32 + kg * 8);
        f32x4 s = {};
        s = __builtin_amdgcn_mfma_f32_16x16x32_bf16(kf0, qf0, s, 0, 0, 0);
        s = __builtin_amdgcn_mfma_f32_16x16x32_bf16(kf1, qf1, s, 0, 0, 0);
#pragma unroll
        for (int v = 0; v < 4; ++v) vals[nt * 4 + v] = s[v];
      }
      if (t == tmax_w) {  // diagonal tile: mask k > q
#pragma unroll
        for (int nt = 0; nt < 4; ++nt)
#pragma unroll
          for (int v = 0; v < 4; ++v)
            if (kv0 + nt * 16 + kg * 4 + v > qrow) vals[nt * 4 + v] = -3e30f;
      }
      float pmax = vals[0];
#pragma unroll
      for (int ii = 1; ii < 16; ++ii) pmax = fmaxf(pmax, vals[ii]);
      pmax = fmaxf(pmax, __shfl_xor(pmax, 16));
      pmax = fmaxf(pmax, __shfl_xor(pmax, 32));
      const float m_new = fmaxf(m_run, pmax);
      const float alpha = __expf(m_run - m_new);
      float psum = 0.f;
#pragma unroll
      for (int ii = 0; ii < 16; ++ii) {
        float p = __expf(vals[ii] - m_new);
        vals[ii] = p;
        psum += p;
      }
      psum += __shfl_xor(psum, 16);
      psum += __shfl_xor(psum, 32);
      l_run = l_run * alpha + psum;
      m_run = m_new;

      // P -> LDS in A-frag layout (bf16), same-wave write->read (DS in-order within wave)
#pragma unroll
      for (int nt = 0; nt < 4; ++nt) {
        bf16x4 pb;
#pragma unroll
        for (int v = 0; v < 4; ++v) pb[v] = (bf16_t)vals[nt * 4 + v];
        *reinterpret_cast<bf16x4*>(&Pl[wave][r * 72 + nt * 16 + kg * 4]) = pb;
      }
      bf16x8 pa0 = *reinterpret_cast<const bf16x8*>(&Pl[wave][r * 72 + kg * 8]);
      bf16x8 pa1 = *reinterpret_cast<const bf16x8*>(&Pl[wave][r * 72 + 32 + kg * 8]);

      // rescale O by alpha of rows kg*4+v (alpha lives on lanes 0..15 by q-row)
      f32x4 al;
#pragma unroll
      for (int v = 0; v < 4; ++v) al[v] = __shfl(alpha, kg * 4 + v);
#pragma unroll
      for (int dt = 0; dt < 4; ++dt)
#pragma unroll
        for (int v = 0; v < 4; ++v) oacc[dt][v] *= al[v];

      // O += P V : B operand rows = d from Vts
#pragma unroll
      for (int dt = 0; dt < 4; ++dt) {
        bf16x8 vb0 = *reinterpret_cast<const bf16x8*>(Vts + (dt * 16 + r) * 72 + kg * 8);
        oacc[dt] = __builtin_amdgcn_mfma_f32_16x16x32_bf16(pa0, vb0, oacc[dt], 0, 0, 0);
        bf16x8 vb1 = *reinterpret_cast<const bf16x8*>(Vts + (dt * 16 + r) * 72 + 32 + kg * 8);
        oacc[dt] = __builtin_amdgcn_mfma_f32_16x16x32_bf16(pa1, vb1, oacc[dt], 0, 0, 0);
      }
    }

    const float linv = 1.0f / l_run;
    f32x4 il;
#pragma unroll
    for (int v = 0; v < 4; ++v) il[v] = __shfl(linv, kg * 4 + v);
    const size_t orow0 = o_row0 + (size_t)(q0 + wave * 16) * ostride + ocol;
#pragma unroll
    for (int dt = 0; dt < 4; ++dt) {
      const int d = dt * 16 + r;
#pragma unroll
      for (int v = 0; v < 4; ++v)
        O[orow0 + (size_t)(kg * 4 + v) * ostride + d] = f2b_rne(oacc[dt][v] * il[v]);
    }
  }
}

// ---------------- launcher ----------------
extern "C" void kernel_launch(void* const* d_in, const int* in_sizes, int n_in,
                              void* d_out, int out_size, void* d_ws, size_t ws_size,
                              hipStream_t stream) {
  const float* x  = (const float*)d_in[0];
  const float* Wq = (const float*)d_in[1];
  const float* Wk = (const float*)d_in[2];
  const float* Wv = (const float*)d_in[3];
  const float* Wo = (const float*)d_in[4];

  // ws layout (72 MB peak):
  //  phase 1 (QKV GEMM):  xb [0,16) | wqb|wkb|wvb [16,22) | qkv [24,72)
  //  phase 2 (transpose/flash): vt [0,16) (xb dead) | qkv [24,72); flash writes O in-place
  //          into qkv Q-columns (no separate ob buffer)
  //  phase 3 (Wo GEMM):   wob [16,18) (wqb dead) | qkv as A (lda=3072) -> d_out
  char* ws = (char*)d_ws;
  bf16_t* xb  = (bf16_t*)(ws);
  bf16_t* wqb = (bf16_t*)(ws + (16u << 20));
  bf16_t* wkb = (bf16_t*)(ws + (18u << 20));
  bf16_t* wvb = (bf16_t*)(ws + (20u << 20));
  bf16_t* qkv = (bf16_t*)(ws + (24u << 20));
  bf16_t* vt  = (bf16_t*)(ws);                 // 16 MB, after xb is dead
  bf16_t* wob = (bf16_t*)(ws + (16u << 20));   // 2 MB, after wqb is dead

  const int NX = 4 * 2048 * 1024;
  const int NW = 1024 * 1024;
  cast_f32_bf16<<<NX / 2048, 256, 0, stream>>>(x,  (unsigned short*)xb,  NX);
  cast_f32_bf16<<<NW / 2048, 256, 0, stream>>>(Wq, (unsigned short*)wqb, NW);
  cast_f32_bf16<<<NW / 2048, 256, 0, stream>>>(Wk, (unsigned short*)wkb, NW);
  cast_f32_bf16<<<NW / 2048, 256, 0, stream>>>(Wv, (unsigned short*)wvb, NW);

  // fused QKV projection: [8192,1024] x [3072,1024]^T -> [8192,3072]; 1/sqrt(dk) on Q cols
  gemm_bt<0><<<dim3(3072 / 128, 8192 / 128), 256, 0, stream>>>(
      xb, wqb, qkv, 8192, 3072, 1024, 1024, 0.125f, 1024);

  transpose_v<<<dim3(2048 / 64, 64), 256, 0, stream>>>(qkv, vt);

  // Wo cast into dead wqb slot (runs after QKV GEMM in stream order)
  cast_f32_bf16<<<NW / 2048, 256, 0, stream>>>(Wo, (unsigned short*)wob, NW);

  flash_attn<<<dim3(8, 64), 512, 0, stream>>>(qkv, vt, (unsigned short*)qkv, 3072);

  // output projection: A = attn output in qkv Q-columns (lda=3072)
  gemm_bt<1><<<dim3(1024 / 128, 8192 / 128), 256, 0, stream>>>(
      qkv, wob, d_out, 8192, 1024, 1024, 3072, 1.0f, 0);
}